// Round 5
// baseline (168.796 us; speedup 1.0000x reference)
//
#include <hip/hip_runtime.h>

#define EPSF 1e-10f

constexpr unsigned KEY15 = 0xBFC00000u;  // f2key(1.5f), bucket-aligned
constexpr int BUCK0 = 0xBFC;             // first tracked bucket (3068)
constexpr int NB2   = 4096 - BUCK0;      // 1028 tracked buckets
constexpr int NBKT  = 4096;
constexpr int NREP  = 8;                 // replicas per bucket (bucket-major!)
constexpr int LHSZ  = NB2 + 64;          // + 64 per-lane dummy slots
constexpr int NGRP  = 64;                // stat spreading lines

typedef float pf4 __attribute__((ext_vector_type(4)));
typedef int   pi4 __attribute__((ext_vector_type(4)));

// ---------- workspace layout (words) ----------
// stat lines: 64 x 16 words (one 64B line each): [0]=np [1]=qc [2]=psig [3]=plos
// rep: BUCKET-MAJOR [NB2][NREP] so finalize reads a bucket's 8 replicas as
//      two dwordx4 (round-4 tail was latency-chained scalar coherent loads).
constexpr int STAT_OFF = 0;
constexpr int REP_OFF  = STAT_OFF + NGRP * 16;       // 1024
constexpr int LOW_OFF  = REP_OFF + NB2 * NREP;       // fallback hist (NBKT)
constexpr int ZERO_TOT = LOW_OFF + NBKT;             // ~13.3k words

__device__ __forceinline__ float sigmoidf_(float x) {
    return 1.0f / (1.0f + expf(-x));
}
__device__ __forceinline__ float softplusf_(float x) {
    return fmaxf(x, 0.0f) + log1pf(expf(-fabsf(x)));
}
__device__ __forceinline__ unsigned f2key(float x) {
    unsigned b = __float_as_uint(x);
    return b ^ ((unsigned)((int)b >> 31) | 0x80000000u);
}
__device__ __forceinline__ float key2f(unsigned k) {
    unsigned b = (k & 0x80000000u) ? (k & 0x7FFFFFFFu) : ~k;
    return __uint_as_float(b);
}

// ---------------------------------------------------------------------------
__global__ void zeroAll(unsigned* ws) {
    int stride = gridDim.x * 256;
    for (int i = blockIdx.x * 256 + threadIdx.x; i < ZERO_TOT; i += stride)
        ws[i] = 0u;
}

// Scan kernel = round-0 k1 structure + spread-line stat atomics. NO ticket,
// NO last-block tail: rounds 0/4 comparison showed dispatch gaps are ~free
// in this harness (6 vs 2 dispatches, same 160us total) while the in-kernel
// ticket+serial-tail cost ~14us on the critical path. The dispatch boundary
// is the grid barrier (HSA kernel-end release / kernel-start acquire —
// empirically validated by round 0's redR reading rep with plain loads).
__global__ __launch_bounds__(256) void scanK(const float* __restrict__ preds,
                                             const int* __restrict__ targs, int N,
                                             unsigned* __restrict__ ws) {
    __shared__ int lh[LHSZ];
    __shared__ float rp[4], rs[4], rl[4], rq[4];

    unsigned* rep = ws + REP_OFF;

    for (int i = threadIdx.x; i < LHSZ; i += 256) lh[i] = 0;
    __syncthreads();

    float pc = 0.f, psig = 0.f, plos = 0.f;
    const int tid = threadIdx.x;
    const int lane = tid & 63;
    const int w = tid >> 6;
    const int dummy = NB2 + lane;            // per-lane dummy slot

    int nfull = N >> 13;                     // full 8192-element tiles
    for (int grp = blockIdx.x; grp < nfull; grp += gridDim.x) {
        size_t ebase = ((size_t)grp << 13) + ((size_t)w << 11) + ((size_t)lane << 2);
        const float* pp  = preds + ebase;        // wave tile: 2048 elements
        const float* pp2 = pp + 1024;
        const int*   tp  = targs + ebase;
        const int*   tp2 = tp + 1024;
        pf4 P[8]; pi4 T[8];
        asm volatile(
            "global_load_dwordx4 %0, %16, off\n\t"
            "global_load_dwordx4 %1, %16, off offset:1024\n\t"
            "global_load_dwordx4 %2, %16, off offset:2048\n\t"
            "global_load_dwordx4 %3, %16, off offset:3072\n\t"
            "global_load_dwordx4 %4, %17, off\n\t"
            "global_load_dwordx4 %5, %17, off offset:1024\n\t"
            "global_load_dwordx4 %6, %17, off offset:2048\n\t"
            "global_load_dwordx4 %7, %17, off offset:3072\n\t"
            "global_load_dwordx4 %8, %18, off\n\t"
            "global_load_dwordx4 %9, %18, off offset:1024\n\t"
            "global_load_dwordx4 %10, %18, off offset:2048\n\t"
            "global_load_dwordx4 %11, %18, off offset:3072\n\t"
            "global_load_dwordx4 %12, %19, off\n\t"
            "global_load_dwordx4 %13, %19, off offset:1024\n\t"
            "global_load_dwordx4 %14, %19, off offset:2048\n\t"
            "global_load_dwordx4 %15, %19, off offset:3072\n\t"
            "s_waitcnt vmcnt(0)"
            : "=&v"(P[0]), "=&v"(P[1]), "=&v"(P[2]), "=&v"(P[3]),
              "=&v"(P[4]), "=&v"(P[5]), "=&v"(P[6]), "=&v"(P[7]),
              "=&v"(T[0]), "=&v"(T[1]), "=&v"(T[2]), "=&v"(T[3]),
              "=&v"(T[4]), "=&v"(T[5]), "=&v"(T[6]), "=&v"(T[7])
            : "v"(pp), "v"(pp2), "v"(tp), "v"(tp2)
            : "memory");
#pragma unroll
        for (int g = 0; g < 8; g++) {
            pf4 pv = P[g]; pi4 tv = T[g];
#pragma unroll
            for (int j = 0; j < 4; j++) {
                float x = pv[j];
                unsigned key = f2key(x);
                int bkt = (int)(key >> 20) - BUCK0;
                bool q = (key >= KEY15) & (tv[j] == 0);
                int addr = q ? bkt : dummy;        // v_cndmask, no exec churn
                atomicAdd(&lh[addr], 1);           // unconditional ds_add
            }
            if (tv[0] | tv[1] | tv[2] | tv[3]) {   // rare positive path
#pragma unroll
                for (int j = 0; j < 4; j++)
                    if (tv[j]) {
                        float x = pv[j];
                        pc += 1.f; psig += sigmoidf_(x); plos += softplusf_(x) - x;
                    }
            }
        }
    }
    // tail elements (N % 8192), last block only
    if (blockIdx.x == gridDim.x - 1) {
        for (int i = (nfull << 13) + tid; i < N; i += 256) {
            float x = preds[i];
            if (targs[i]) { pc += 1.f; psig += sigmoidf_(x); plos += softplusf_(x) - x; }
            else {
                unsigned key = f2key(x);
                if (key >= KEY15) atomicAdd(&lh[(key >> 20) - BUCK0], 1);
            }
        }
    }
    __syncthreads();
    // flush hist (dummy slots >= NB2 ignored) + qualifying count.
    // rep is bucket-major: bucket i, replica (bid&7) -> rep[i*NREP + rsel].
    float qc = 0.f;
    const int rsel = blockIdx.x & (NREP - 1);
    for (int i = tid; i < NB2; i += 256) {
        int c = lh[i];
        if (c) { atomicAdd(&rep[i * NREP + rsel], (unsigned)c); qc += (float)c; }
    }
#pragma unroll
    for (int o = 32; o > 0; o >>= 1) {
        pc   += __shfl_down(pc, o);
        psig += __shfl_down(psig, o);
        plos += __shfl_down(plos, o);
        qc   += __shfl_down(qc, o);
    }
    if ((tid & 63) == 0) { rp[w] = pc; rs[w] = psig; rl[w] = plos; rq[w] = qc; }
    __syncthreads();
    if (tid == 0) {
        unsigned npb = (unsigned)(rp[0] + rp[1] + rp[2] + rp[3] + 0.5f);
        unsigned qcb = (unsigned)(rq[0] + rq[1] + rq[2] + rq[3] + 0.5f);
        float    psb = rs[0] + rs[1] + rs[2] + rs[3];
        float    plb = rl[0] + rl[1] + rl[2] + rl[3];
        unsigned ng  = (gridDim.x < (unsigned)NGRP) ? gridDim.x : (unsigned)NGRP;
        unsigned g   = blockIdx.x % ng;
        unsigned* line = ws + STAT_OFF + g * 16;
        atomicAdd(&line[0], npb);                  // fire-and-forget; kernel
        atomicAdd(&line[1], qcb);                  // end drains them
        atomicAdd((float*)&line[2], psb);
        atomicAdd((float*)&line[3], plb);
    }
}

// finalize: 1 block. Dispatch boundary guarantees visibility of scanK's
// atomics (plain loads OK — proven by round-0 redR/flagK). Stats gather is
// one wave of uint4 loads; replica reduce is 2 dwordx4 per bucket
// (bucket-major rep) instead of 8 latency-chained scalar coherent loads.
__global__ __launch_bounds__(256) void finalizeK(const float* __restrict__ preds,
                                                 const int* __restrict__ targs, int N,
                                                 const unsigned* __restrict__ ws,
                                                 float* __restrict__ out) {
    __shared__ unsigned histH[NB2];
    __shared__ unsigned sa[256], sb[256];
    __shared__ int sb1;
    __shared__ unsigned sr1;
    __shared__ double rds[4], rdl[4];
    __shared__ unsigned s_np, s_k, s_flag;
    __shared__ float s_psig, s_plos;

    const unsigned* rep = ws + REP_OFF;
    const unsigned* low = ws + LOW_OFF;
    const int tid = threadIdx.x;
    const int w = tid >> 6;

    // ---- gather spread stats (one wave of vector loads) ----
    if (tid < 64) {
        uint4 v = *(const uint4*)(ws + STAT_OFF + tid * 16);
        unsigned np_ = v.x, qc_ = v.y;
        float ps_ = __uint_as_float(v.z), pl_ = __uint_as_float(v.w);
#pragma unroll
        for (int o = 32; o > 0; o >>= 1) {
            np_ += __shfl_down(np_, o);
            qc_ += __shfl_down(qc_, o);
            ps_ += __shfl_down(ps_, o);
            pl_ += __shfl_down(pl_, o);
        }
        if (tid == 0) {
            unsigned np = np_;
            unsigned nn = (unsigned)N - np;
            unsigned k = (np == 0u) ? (unsigned)(0.1 * (double)nn)
                                    : ((30u * np < nn) ? 30u * np : nn);
            s_np = np; s_psig = ps_; s_plos = pl_; s_k = k;
            s_flag = (k > qc_) ? 1u : 0u;
        }
    }
    // ---- replica reduce: bucket-major -> 2 x dwordx4 per bucket ----
    for (int i = tid; i < NB2; i += 256) {
        const uint4* p = (const uint4*)(rep + i * NREP);
        uint4 a = p[0], b = p[1];
        histH[i] = ((a.x + a.y) + (a.z + a.w)) + ((b.x + b.y) + (b.z + b.w));
    }
    __syncthreads();

    // ---- fallback low-bucket histogram (pathological inputs only) ----
    if (s_flag) {
        unsigned* loww = (unsigned*)low;
        for (int i = tid; i < N; i += 256) {
            if (!targs[i]) {
                unsigned key = f2key(preds[i]);
                if (key < KEY15) atomicAdd(&loww[key >> 20], 1u);
            }
        }
        __syncthreads();
    }

    // ---- top-k bucket search + analytic sums ----
    {
        int t = tid;
        int base = t * 16;
        unsigned flag = s_flag;
        unsigned c[16]; unsigned tot = 0;
#pragma unroll
        for (int j = 0; j < 16; j++) {
            int b = base + j;
            unsigned s = (b >= BUCK0) ? histH[b - BUCK0] : (flag ? low[b] : 0u);
            c[j] = s; tot += s;
        }
        sa[t] = tot;
        if (t == 0) { sb1 = NBKT; sr1 = 0u; }
        __syncthreads();
        unsigned k = s_k;
        unsigned* src = sa; unsigned* dst = sb;
        for (int off = 1; off < 256; off <<= 1) {
            unsigned v = src[t] + ((t + off < 256) ? src[t + off] : 0u);
            dst[t] = v;
            __syncthreads();
            unsigned* tmp = src; src = dst; dst = tmp;
        }
        if (k > 0u) {
            unsigned above = src[t] - tot;
            if (above < k && above + tot >= k) {
                unsigned cum = above;
                for (int j = 15; j >= 0; j--) {
                    unsigned cc = c[j];
                    if (cum + cc >= k) { sb1 = base + j; sr1 = k - cum; break; }
                    cum += cc;
                }
            }
        }
        __syncthreads();
        int b1 = sb1; unsigned r1 = sr1;
        double ssig = 0.0, ssp = 0.0;
#pragma unroll
        for (int j = 0; j < 16; j++) {
            int b = base + j; unsigned cc = c[j];
            if (cc == 0u) continue;
            bool full = (b > b1);
            bool part = (b == b1) && (r1 > 0u);
            if (!(full || part)) continue;
            float lo = key2f((unsigned)b << 20);
            float hi = (b == NBKT - 1) ? key2f(0xFF7FFFFFu)
                                       : key2f(((unsigned)(b + 1)) << 20);
            if (full) {
                float mid = 0.5f * (lo + hi);
                ssig += (double)cc * (double)sigmoidf_(mid);
                ssp  += (double)cc * (double)softplusf_(mid);
            } else {
                unsigned take = (r1 < cc) ? r1 : cc;
                double q = (double)take / (double)cc;
                float rpv = (float)((double)hi - 0.5 * q * ((double)hi - (double)lo));
                ssig += (double)take * (double)sigmoidf_(rpv);
                ssp  += (double)take * (double)softplusf_(rpv);
            }
        }
#pragma unroll
        for (int o = 32; o > 0; o >>= 1) {
            ssig += __shfl_down(ssig, o);
            ssp  += __shfl_down(ssp, o);
        }
        if ((t & 63) == 0) { rds[w] = ssig; rdl[w] = ssp; }
        __syncthreads();
        if (t == 0) {
            double sns = rds[0] + rds[1] + rds[2] + rds[3];
            double snl = rdl[0] + rdl[1] + rdl[2] + rdl[3];
            unsigned np = s_np;
            float psig2 = s_psig, plos2 = s_plos;
            double denom = (double)psig2 + sns + (double)np;
            double dice = 1.0 - (2.0 * (double)psig2 + (double)EPSF) / (denom + (double)EPSF);
            unsigned totsel = np + k;
            double mean = totsel ? (((double)plos2 + snl) / (double)totsel) : 0.0;
            out[0] = (float)(dice + mean);
        }
    }
}

// ---------------------------------------------------------------------------
extern "C" void kernel_launch(void* const* d_in, const int* in_sizes, int n_in,
                              void* d_out, int out_size, void* d_ws, size_t ws_size,
                              hipStream_t stream) {
    const float* preds = (const float*)d_in[0];
    const int*   targs = (const int*)d_in[1];
    float* out = (float*)d_out;
    int N = in_sizes[0];
    unsigned* ws = (unsigned*)d_ws;

    int nfull = N >> 13;
    int grid = nfull + ((N & 8191) ? 1 : 0);
    if (grid < 1) grid = 1;
    if (grid > 4096) grid = 4096;   // blocks grid-stride past

    zeroAll<<<64, 256, 0, stream>>>(ws);
    scanK<<<grid, 256, 0, stream>>>(preds, targs, N, ws);
    finalizeK<<<1, 256, 0, stream>>>(preds, targs, N, ws, out);
}

// Round 6
// 158.866 us; speedup vs baseline: 1.0625x; 1.0625x over previous
//
#include <hip/hip_runtime.h>

#define EPSF 1e-10f

constexpr unsigned KEY15 = 0xBFC00000u;  // f2key(1.5f), bucket-aligned
constexpr int BUCK0 = 0xBFC;             // first tracked bucket (3068)
constexpr int NB2   = 4096 - BUCK0;      // 1028 tracked buckets
constexpr int NBKT  = 4096;
constexpr int NREP  = 8;                 // replica rows == NXCD (XCD-aligned!)
constexpr int LHSZ  = NB2 + 64;          // + 64 per-lane dummy slots

typedef float pf4 __attribute__((ext_vector_type(4)));
typedef int   pi4 __attribute__((ext_vector_type(4)));

// ---------- workspace layout (words) ----------
constexpr int BSTAT_OFF = 64;                       // 4096 float4 (16384 words)
constexpr int REP_OFF   = BSTAT_OFF + 4096 * 4;     // replica-major [NREP][NB2]
constexpr int LOW_OFF   = REP_OFF + NREP * NB2;     // fallback hist (NBKT)
constexpr int ZERO_N    = NREP * NB2;               // only rep needs zeroing

__device__ __forceinline__ float sigmoidf_(float x) {
    return 1.0f / (1.0f + expf(-x));
}
__device__ __forceinline__ float softplusf_(float x) {
    return fmaxf(x, 0.0f) + log1pf(expf(-fabsf(x)));
}
__device__ __forceinline__ unsigned f2key(float x) {
    unsigned b = __float_as_uint(x);
    return b ^ ((unsigned)((int)b >> 31) | 0x80000000u);
}
__device__ __forceinline__ float key2f(unsigned k) {
    unsigned b = (k & 0x80000000u) ? (k & 0x7FFFFFFFu) : ~k;
    return __uint_as_float(b);
}
__device__ __forceinline__ unsigned cload(const unsigned* p) {
    return __hip_atomic_load(p, __ATOMIC_RELAXED, __HIP_MEMORY_SCOPE_AGENT);
}

// ---------------------------------------------------------------------------
__global__ void zeroAll(unsigned* ws) {
    int stride = gridDim.x * 256;
    for (int i = blockIdx.x * 256 + threadIdx.x; i < ZERO_N; i += stride)
        ws[REP_OFF + i] = 0u;
}

// scanK == round-0 k1 VERBATIM (proven 46us). Round-5 post-mortem: the
// bucket-major rep flush put all 8 replicas of a bucket in one 64B line ->
// device-scope atomics from all 8 XCDs ping-ponged each popular line through
// the coherence point (WRITE_SIZE 200->977KB, +12us). Replica-major with
// rsel = bid&7 is XCD-ALIGNED (blockIdx round-robins across 8 XCDs): each
// replica region is only RMW'd by one XCD -> lines stay in that XCD's L2.
// NREP == NXCD is load-bearing. Per-block stats go out as a plain float4
// store to bstat[bid] (distinct lines, no RMW, proven cheap).
__global__ __launch_bounds__(256) void scanK(const float* __restrict__ preds,
                                             const int* __restrict__ targs, int N,
                                             float4* __restrict__ bstat,
                                             unsigned* __restrict__ rep) {
    __shared__ int lh[LHSZ];
    for (int i = threadIdx.x; i < LHSZ; i += 256) lh[i] = 0;
    __syncthreads();

    float pc = 0.f, psig = 0.f, plos = 0.f;
    const int tid = threadIdx.x;
    const int lane = tid & 63;
    const int w = tid >> 6;
    const int dummy = NB2 + lane;            // per-lane dummy slot

    int nfull = N >> 13;                     // full 8192-element tiles
    for (int grp = blockIdx.x; grp < nfull; grp += gridDim.x) {
        size_t ebase = ((size_t)grp << 13) + ((size_t)w << 11) + ((size_t)lane << 2);
        const float* pp  = preds + ebase;        // wave tile: 2048 elements
        const float* pp2 = pp + 1024;
        const int*   tp  = targs + ebase;
        const int*   tp2 = tp + 1024;
        pf4 P[8]; pi4 T[8];
        asm volatile(
            "global_load_dwordx4 %0, %16, off\n\t"
            "global_load_dwordx4 %1, %16, off offset:1024\n\t"
            "global_load_dwordx4 %2, %16, off offset:2048\n\t"
            "global_load_dwordx4 %3, %16, off offset:3072\n\t"
            "global_load_dwordx4 %4, %17, off\n\t"
            "global_load_dwordx4 %5, %17, off offset:1024\n\t"
            "global_load_dwordx4 %6, %17, off offset:2048\n\t"
            "global_load_dwordx4 %7, %17, off offset:3072\n\t"
            "global_load_dwordx4 %8, %18, off\n\t"
            "global_load_dwordx4 %9, %18, off offset:1024\n\t"
            "global_load_dwordx4 %10, %18, off offset:2048\n\t"
            "global_load_dwordx4 %11, %18, off offset:3072\n\t"
            "global_load_dwordx4 %12, %19, off\n\t"
            "global_load_dwordx4 %13, %19, off offset:1024\n\t"
            "global_load_dwordx4 %14, %19, off offset:2048\n\t"
            "global_load_dwordx4 %15, %19, off offset:3072\n\t"
            "s_waitcnt vmcnt(0)"
            : "=&v"(P[0]), "=&v"(P[1]), "=&v"(P[2]), "=&v"(P[3]),
              "=&v"(P[4]), "=&v"(P[5]), "=&v"(P[6]), "=&v"(P[7]),
              "=&v"(T[0]), "=&v"(T[1]), "=&v"(T[2]), "=&v"(T[3]),
              "=&v"(T[4]), "=&v"(T[5]), "=&v"(T[6]), "=&v"(T[7])
            : "v"(pp), "v"(pp2), "v"(tp), "v"(tp2)
            : "memory");
#pragma unroll
        for (int g = 0; g < 8; g++) {
            pf4 pv = P[g]; pi4 tv = T[g];
#pragma unroll
            for (int j = 0; j < 4; j++) {
                float x = pv[j];
                unsigned key = f2key(x);
                int bkt = (int)(key >> 20) - BUCK0;
                bool q = (key >= KEY15) & (tv[j] == 0);
                int addr = q ? bkt : dummy;        // v_cndmask, no exec churn
                atomicAdd(&lh[addr], 1);           // unconditional ds_add
            }
            if (tv[0] | tv[1] | tv[2] | tv[3]) {   // rare positive path
#pragma unroll
                for (int j = 0; j < 4; j++)
                    if (tv[j]) {
                        float x = pv[j];
                        pc += 1.f; psig += sigmoidf_(x); plos += softplusf_(x) - x;
                    }
            }
        }
    }
    // tail elements (N % 8192), last block only
    if (blockIdx.x == gridDim.x - 1) {
        for (int i = (nfull << 13) + tid; i < N; i += 256) {
            float x = preds[i];
            if (targs[i]) { pc += 1.f; psig += sigmoidf_(x); plos += softplusf_(x) - x; }
            else {
                unsigned key = f2key(x);
                if (key >= KEY15) atomicAdd(&lh[(key >> 20) - BUCK0], 1);
            }
        }
    }
    __syncthreads();
    // flush hist (dummy slots >= NB2 ignored) + qualifying count
    float qc = 0.f;
    unsigned* my = rep + (unsigned)(blockIdx.x & (NREP - 1)) * NB2;
    for (int i = tid; i < NB2; i += 256) {
        int c = lh[i];
        if (c) { atomicAdd(&my[i], (unsigned)c); qc += (float)c; }
    }
#pragma unroll
    for (int o = 32; o > 0; o >>= 1) {
        pc   += __shfl_down(pc, o);
        psig += __shfl_down(psig, o);
        plos += __shfl_down(plos, o);
        qc   += __shfl_down(qc, o);
    }
    __shared__ float rp[4], rs[4], rl[4], rq[4];
    if ((tid & 63) == 0) { rp[w] = pc; rs[w] = psig; rl[w] = plos; rq[w] = qc; }
    __syncthreads();
    if (tid == 0)
        bstat[blockIdx.x] = make_float4(rp[0] + rp[1] + rp[2] + rp[3],
                                        rs[0] + rs[1] + rs[2] + rs[3],
                                        rl[0] + rl[1] + rl[2] + rl[3],
                                        rq[0] + rq[1] + rq[2] + rq[3]);
}

// finalizeK: 1 block, merges round-0's flagK + redR + lowH + finalize into a
// single trailing dispatch (~1.3us fixed cost per dispatch saved x3).
// Dispatch boundary = visibility barrier (proven in r0: plain loads after
// another kernel's atomics/stores are coherent).
__global__ __launch_bounds__(256) void finalizeK(const float* __restrict__ preds,
                                                 const int* __restrict__ targs, int N,
                                                 int nblocks,
                                                 unsigned* __restrict__ ws,
                                                 float* __restrict__ out) {
    __shared__ unsigned histH[NB2];
    __shared__ unsigned sa[256], sb[256];
    __shared__ int sb1;
    __shared__ unsigned sr1;
    __shared__ float rp[4], rs[4], rl[4], rq[4];
    __shared__ double rds[4], rdl[4];
    __shared__ unsigned s_np, s_k, s_flag;
    __shared__ float s_psig, s_plos;

    const float4*   bstat = (const float4*)(ws + BSTAT_OFF);
    const unsigned* rep   = ws + REP_OFF;
    unsigned*       low   = ws + LOW_OFF;
    const int tid = threadIdx.x;
    const int w = tid >> 6;

    // ---- stage A: reduce per-block stats (flagK) ----
    {
        float pc = 0.f, ps = 0.f, pl = 0.f, qt = 0.f;
        for (int i = tid; i < nblocks; i += 256) {
            float4 v = bstat[i];
            pc += v.x; ps += v.y; pl += v.z; qt += v.w;
        }
#pragma unroll
        for (int o = 32; o > 0; o >>= 1) {
            pc += __shfl_down(pc, o);
            ps += __shfl_down(ps, o);
            pl += __shfl_down(pl, o);
            qt += __shfl_down(qt, o);
        }
        if ((tid & 63) == 0) { rp[w] = pc; rs[w] = ps; rl[w] = pl; rq[w] = qt; }
        __syncthreads();
        if (tid == 0) {
            unsigned np = (unsigned)(rp[0] + rp[1] + rp[2] + rp[3] + 0.5f);
            float psT = rs[0] + rs[1] + rs[2] + rs[3];
            float plT = rl[0] + rl[1] + rl[2] + rl[3];
            unsigned qtT = (unsigned)(rq[0] + rq[1] + rq[2] + rq[3] + 0.5f);
            unsigned nn = (unsigned)N - np;
            unsigned k = (np == 0u) ? (unsigned)(0.1 * (double)nn)
                                    : ((30u * np < nn) ? 30u * np : nn);
            s_np = np; s_psig = psT; s_plos = plT; s_k = k;
            s_flag = (k > qtT) ? 1u : 0u;
        }
    }

    // ---- stage B: replica reduce (redR), vectorized: replica-major is
    //      bucket-contiguous, so 4 buckets = one uint4 per replica ----
    for (int t = tid; t * 4 < NB2; t += 256) {
        unsigned a0 = 0, a1 = 0, a2 = 0, a3 = 0;
#pragma unroll
        for (int r = 0; r < NREP; r++) {
            uint4 v = *(const uint4*)(rep + r * NB2 + t * 4);
            a0 += v.x; a1 += v.y; a2 += v.z; a3 += v.w;
        }
        histH[t * 4 + 0] = a0; histH[t * 4 + 1] = a1;
        histH[t * 4 + 2] = a2; histH[t * 4 + 3] = a3;
    }
    __syncthreads();

    // ---- stage C: fallback low-bucket histogram (pathological only) ----
    if (s_flag) {
        for (int i = tid; i < NBKT; i += 256) low[i] = 0u;   // lazy zero
        __syncthreads();
        for (int i = tid; i < N; i += 256) {
            if (!targs[i]) {
                unsigned key = f2key(preds[i]);
                if (key < KEY15) atomicAdd(&low[key >> 20], 1u);
            }
        }
        __syncthreads();
    }

    // ---- stage D: top-k bucket search + analytic sums ----
    {
        int t = tid;
        int base = t * 16;
        unsigned flag = s_flag;
        unsigned c[16]; unsigned tot = 0;
#pragma unroll
        for (int j = 0; j < 16; j++) {
            int b = base + j;
            unsigned s = (b >= BUCK0) ? histH[b - BUCK0] : (flag ? cload(&low[b]) : 0u);
            c[j] = s; tot += s;
        }
        sa[t] = tot;
        if (t == 0) { sb1 = NBKT; sr1 = 0u; }
        __syncthreads();
        unsigned k = s_k;
        unsigned* src = sa; unsigned* dst = sb;
        for (int off = 1; off < 256; off <<= 1) {
            unsigned v = src[t] + ((t + off < 256) ? src[t + off] : 0u);
            dst[t] = v;
            __syncthreads();
            unsigned* tmp = src; src = dst; dst = tmp;
        }
        if (k > 0u) {
            unsigned above = src[t] - tot;
            if (above < k && above + tot >= k) {
                unsigned cum = above;
                for (int j = 15; j >= 0; j--) {
                    unsigned cc = c[j];
                    if (cum + cc >= k) { sb1 = base + j; sr1 = k - cum; break; }
                    cum += cc;
                }
            }
        }
        __syncthreads();
        int b1 = sb1; unsigned r1 = sr1;
        double ssig = 0.0, ssp = 0.0;
#pragma unroll
        for (int j = 0; j < 16; j++) {
            int b = base + j; unsigned cc = c[j];
            if (cc == 0u) continue;
            bool full = (b > b1);
            bool part = (b == b1) && (r1 > 0u);
            if (!(full || part)) continue;
            float lo = key2f((unsigned)b << 20);
            float hi = (b == NBKT - 1) ? key2f(0xFF7FFFFFu)
                                       : key2f(((unsigned)(b + 1)) << 20);
            if (full) {
                float mid = 0.5f * (lo + hi);
                ssig += (double)cc * (double)sigmoidf_(mid);
                ssp  += (double)cc * (double)softplusf_(mid);
            } else {
                unsigned take = (r1 < cc) ? r1 : cc;
                double q = (double)take / (double)cc;
                float rpv = (float)((double)hi - 0.5 * q * ((double)hi - (double)lo));
                ssig += (double)take * (double)sigmoidf_(rpv);
                ssp  += (double)take * (double)softplusf_(rpv);
            }
        }
#pragma unroll
        for (int o = 32; o > 0; o >>= 1) {
            ssig += __shfl_down(ssig, o);
            ssp  += __shfl_down(ssp, o);
        }
        if ((t & 63) == 0) { rds[w] = ssig; rdl[w] = ssp; }
        __syncthreads();
        if (t == 0) {
            double sns = rds[0] + rds[1] + rds[2] + rds[3];
            double snl = rdl[0] + rdl[1] + rdl[2] + rdl[3];
            unsigned np = s_np;
            float psig2 = s_psig, plos2 = s_plos;
            double denom = (double)psig2 + sns + (double)np;
            double dice = 1.0 - (2.0 * (double)psig2 + (double)EPSF) / (denom + (double)EPSF);
            unsigned totsel = np + k;
            double mean = totsel ? (((double)plos2 + snl) / (double)totsel) : 0.0;
            out[0] = (float)(dice + mean);
        }
    }
}

// ---------------------------------------------------------------------------
extern "C" void kernel_launch(void* const* d_in, const int* in_sizes, int n_in,
                              void* d_out, int out_size, void* d_ws, size_t ws_size,
                              hipStream_t stream) {
    const float* preds = (const float*)d_in[0];
    const int*   targs = (const int*)d_in[1];
    float* out = (float*)d_out;
    int N = in_sizes[0];

    unsigned* ws  = (unsigned*)d_ws;
    float4* bstat = (float4*)(ws + BSTAT_OFF);
    unsigned* rep = ws + REP_OFF;

    int nfull = N >> 13;
    int grid = nfull + ((N & 8191) ? 1 : 0);
    if (grid < 1) grid = 1;
    if (grid > 4096) grid = 4096;   // bstat bound; blocks grid-stride past

    zeroAll<<<32, 256, 0, stream>>>(ws);
    scanK<<<grid, 256, 0, stream>>>(preds, targs, N, bstat, rep);
    finalizeK<<<1, 256, 0, stream>>>(preds, targs, N, grid, ws, out);
}